// Round 1
// baseline (563.484 us; speedup 1.0000x reference)
//
#include <hip/hip_runtime.h>
#include <hip/hip_bf16.h>
#include <stdint.h>

// MoE: B=4,S=2048,D=512,F=2048,E=8,K=2.  T = B*S = 8192 tokens.
#define TT 8192
#define DD 512
#define FF 2048
#define EE 8

typedef __attribute__((ext_vector_type(8))) short bf16x8;
typedef __attribute__((ext_vector_type(4))) float f32x4;

static __device__ __forceinline__ unsigned short f2b(float f) {
  union { __hip_bfloat16 b; unsigned short u; } cv;
  cv.b = __float2bfloat16(f);
  return cv.u;
}

// ---------------- zero y + control block ----------------
__global__ void k_zero(float4* y4, int n4, int* ctrl) {
  int i = blockIdx.x * blockDim.x + threadIdx.x;
  int stride = gridDim.x * blockDim.x;
  for (; i < n4; i += stride) y4[i] = make_float4(0.f, 0.f, 0.f, 0.f);
  if (blockIdx.x == 0 && threadIdx.x < 64) ctrl[threadIdx.x] = 0;
}

// ---------------- convert x -> bf16 ----------------
__global__ void k_cvt_x(const float4* x4, ushort4* xb4, int n4) {
  int i = blockIdx.x * blockDim.x + threadIdx.x;
  int stride = gridDim.x * blockDim.x;
  for (; i < n4; i += stride) {
    float4 v = x4[i];
    ushort4 o;
    o.x = f2b(v.x); o.y = f2b(v.y); o.z = f2b(v.z); o.w = f2b(v.w);
    xb4[i] = o;
  }
}

// ---------------- transpose+convert: in[e][M][N] f32 -> out[e][N][M] bf16 ----
__global__ void k_tcvt(const float* in, unsigned short* out, int M, int N) {
  __shared__ float tile[32][33];
  int z = blockIdx.z;
  const float* src = in + (size_t)z * M * N;
  unsigned short* dst = out + (size_t)z * M * N;
  int rb = blockIdx.y * 32, cb = blockIdx.x * 32;
  int tx = threadIdx.x, ty = threadIdx.y;
#pragma unroll
  for (int i = 0; i < 4; i++)
    tile[ty + i * 8][tx] = src[(size_t)(rb + ty + i * 8) * N + cb + tx];
  __syncthreads();
#pragma unroll
  for (int i = 0; i < 4; i++)
    dst[(size_t)(cb + ty + i * 8) * M + rb + tx] = f2b(tile[tx][ty + i * 8]);
}

// ---------------- gating: fp32 logits, top-2, softmax ----------------
__global__ void k_gate(const float* __restrict__ x, const float* __restrict__ Wg,
                       int* te, float* tw, int* ctrl) {
  int wid = threadIdx.x >> 6, lane = threadIdx.x & 63;
  int t = blockIdx.x * 4 + wid;
  float acc[EE];
#pragma unroll
  for (int e = 0; e < EE; e++) acc[e] = 0.f;
  const float* xr = x + (size_t)t * DD;
  for (int d = lane; d < DD; d += 64) {
    float xv = xr[d];
    const float* wg = Wg + d * EE;
    float4 a = *(const float4*)wg;
    float4 b = *(const float4*)(wg + 4);
    acc[0] += xv * a.x; acc[1] += xv * a.y; acc[2] += xv * a.z; acc[3] += xv * a.w;
    acc[4] += xv * b.x; acc[5] += xv * b.y; acc[6] += xv * b.z; acc[7] += xv * b.w;
  }
#pragma unroll
  for (int e = 0; e < EE; e++)
    for (int o = 32; o; o >>= 1) acc[e] += __shfl_xor(acc[e], o);
  if (lane == 0) {
    int e1 = 0; float v1 = acc[0];
    for (int e = 1; e < EE; e++) if (acc[e] > v1) { v1 = acc[e]; e1 = e; }
    int e2 = -1; float v2 = -INFINITY;
    for (int e = 0; e < EE; e++) if (e != e1 && acc[e] > v2) { v2 = acc[e]; e2 = e; }
    float ex = __expf(v2 - v1);
    float w1 = 1.f / (1.f + ex);
    float w2 = ex / (1.f + ex);
    te[t * 2] = e1; te[t * 2 + 1] = e2;
    tw[t * 2] = w1; tw[t * 2 + 1] = w2;
    atomicAdd(&ctrl[e1], 1);
    atomicAdd(&ctrl[e2], 1);
  }
}

// ---------------- scan counts -> offsets ----------------
__global__ void k_scan(int* ctrl) {
  if (threadIdx.x == 0) {
    int s = 0;
    for (int e = 0; e < EE; e++) { ctrl[8 + e] = s; s += ctrl[e]; }
    ctrl[16] = s;
    for (int e = 0; e < EE; e++) ctrl[17 + e] = ctrl[8 + e];
  }
}

// ---------------- scatter tokens to expert-sorted rows ----------------
__global__ void k_scatter(const int* te, const float* tw, int* ctrl,
                          int* perm, float* pw) {
  int t = blockIdx.x * blockDim.x + threadIdx.x;
  if (t < TT) {
#pragma unroll
    for (int k = 0; k < 2; k++) {
      int e = te[2 * t + k];
      int pos = atomicAdd(&ctrl[17 + e], 1);
      perm[pos] = t;
      pw[pos] = tw[2 * t + k];
    }
  }
}

// ---------------- GEMM1: h[pos][f] = pw * silu(x@W) * (x@V)  (bf16 MFMA) ----
// Tile: 64 rows x 128 f-cols, BK=32. 4 waves (2x2).
__launch_bounds__(256)
__global__ void k_ffn1(const unsigned short* __restrict__ xb,
                       const unsigned short* __restrict__ Wt,
                       const unsigned short* __restrict__ Vt,
                       const int* __restrict__ perm, const float* __restrict__ pw,
                       const int* __restrict__ ctrl, unsigned short* __restrict__ h) {
  int e = blockIdx.z, ftile = blockIdx.y, mt = blockIdx.x;
  int r0 = ctrl[8 + e], r1 = ctrl[9 + e];
  int row0 = r0 + mt * 64;
  if (row0 >= r1) return;
  int last = r1 - 1;

  __shared__ __align__(16) short As[64 * 32];
  __shared__ __align__(16) short Bw[128 * 32];
  __shared__ __align__(16) short Bv[128 * 32];

  int tid = threadIdx.x;
  int lane = tid & 63, wid = tid >> 6;
  int wm = (wid >> 1) * 32, wn = (wid & 1) * 64;

  // staging addresses (A rows are gathered through perm, clamped to valid)
  int sArow = row0 + (tid >> 2);
  if (sArow > last) sArow = last;
  const unsigned short* agp = xb + (size_t)perm[sArow] * DD + (tid & 3) * 8;
  int f0 = ftile * 128;
  const unsigned short* wgp0 = Wt + ((size_t)e * FF + f0 + (tid >> 2)) * DD + (tid & 3) * 8;
  const unsigned short* wgp1 = wgp0 + (size_t)64 * DD;
  const unsigned short* vgp0 = Vt + ((size_t)e * FF + f0 + (tid >> 2)) * DD + (tid & 3) * 8;
  const unsigned short* vgp1 = vgp0 + (size_t)64 * DD;
  short* aw = &As[(tid >> 2) * 32 + (tid & 3) * 8];
  short* bw0 = &Bw[(tid >> 2) * 32 + (tid & 3) * 8];
  short* bw1 = bw0 + 64 * 32;
  short* bv0 = &Bv[(tid >> 2) * 32 + (tid & 3) * 8];
  short* bv1 = bv0 + 64 * 32;

  f32x4 zz = {0.f, 0.f, 0.f, 0.f};
  f32x4 accw[2][4], accv[2][4];
#pragma unroll
  for (int m = 0; m < 2; m++)
#pragma unroll
    for (int n = 0; n < 4; n++) { accw[m][n] = zz; accv[m][n] = zz; }

  int arow_l = wm + (lane & 15);
  int kb = (lane >> 4) * 8;

  for (int k0 = 0; k0 < DD; k0 += 32) {
    *(int4*)aw  = *(const int4*)(agp + k0);
    *(int4*)bw0 = *(const int4*)(wgp0 + k0);
    *(int4*)bw1 = *(const int4*)(wgp1 + k0);
    *(int4*)bv0 = *(const int4*)(vgp0 + k0);
    *(int4*)bv1 = *(const int4*)(vgp1 + k0);
    __syncthreads();
    bf16x8 a0 = *(bf16x8*)&As[arow_l * 32 + kb];
    bf16x8 a1 = *(bf16x8*)&As[(arow_l + 16) * 32 + kb];
#pragma unroll
    for (int n = 0; n < 4; n++) {
      int fc = wn + n * 16 + (lane & 15);
      bf16x8 bwf = *(bf16x8*)&Bw[fc * 32 + kb];
      bf16x8 bvf = *(bf16x8*)&Bv[fc * 32 + kb];
      accw[0][n] = __builtin_amdgcn_mfma_f32_16x16x32_bf16(a0, bwf, accw[0][n], 0, 0, 0);
      accw[1][n] = __builtin_amdgcn_mfma_f32_16x16x32_bf16(a1, bwf, accw[1][n], 0, 0, 0);
      accv[0][n] = __builtin_amdgcn_mfma_f32_16x16x32_bf16(a0, bvf, accv[0][n], 0, 0, 0);
      accv[1][n] = __builtin_amdgcn_mfma_f32_16x16x32_bf16(a1, bvf, accv[1][n], 0, 0, 0);
    }
    __syncthreads();
  }

  // epilogue: h = silu(aw)*av * gateweight, bf16 store
#pragma unroll
  for (int m = 0; m < 2; m++) {
    int rbase = row0 + wm + m * 16 + (lane >> 4) * 4;
#pragma unroll
    for (int reg = 0; reg < 4; reg++) {
      int r = rbase + reg;
      if (r > last) continue;
      float pwv = pw[r];
      size_t hrow = (size_t)r * FF;
#pragma unroll
      for (int n = 0; n < 4; n++) {
        float a = accw[m][n][reg];
        float b = accv[m][n][reg];
        float hv = a / (1.f + __expf(-a)) * b * pwv;
        int col = f0 + wn + n * 16 + (lane & 15);
        h[hrow + col] = f2b(hv);
      }
    }
  }
}

// ---------------- GEMM2: y[perm[pos]][d] += h[pos] @ W2t[e]  ----------------
// Tile: 64 rows x 128 d-cols, BK=32 over F=2048.
__launch_bounds__(256)
__global__ void k_ffn2(const unsigned short* __restrict__ h,
                       const unsigned short* __restrict__ W2t,
                       const int* __restrict__ perm, const int* __restrict__ ctrl,
                       float* __restrict__ y) {
  int e = blockIdx.z, dt = blockIdx.y, mt = blockIdx.x;
  int r0 = ctrl[8 + e], r1 = ctrl[9 + e];
  int row0 = r0 + mt * 64;
  if (row0 >= r1) return;
  int last = r1 - 1;

  __shared__ __align__(16) short As[64 * 32];
  __shared__ __align__(16) short Bs[128 * 32];

  int tid = threadIdx.x;
  int lane = tid & 63, wid = tid >> 6;
  int wm = (wid >> 1) * 32, wn = (wid & 1) * 64;

  int sArow = row0 + (tid >> 2);
  if (sArow > last) sArow = last;
  const unsigned short* agp = h + (size_t)sArow * FF + (tid & 3) * 8;
  int d0 = dt * 128;
  const unsigned short* bgp0 = W2t + ((size_t)e * DD + d0 + (tid >> 2)) * FF + (tid & 3) * 8;
  const unsigned short* bgp1 = bgp0 + (size_t)64 * FF;
  short* aw = &As[(tid >> 2) * 32 + (tid & 3) * 8];
  short* bw0 = &Bs[(tid >> 2) * 32 + (tid & 3) * 8];
  short* bw1 = bw0 + 64 * 32;

  f32x4 zz = {0.f, 0.f, 0.f, 0.f};
  f32x4 acc[2][4];
#pragma unroll
  for (int m = 0; m < 2; m++)
#pragma unroll
    for (int n = 0; n < 4; n++) acc[m][n] = zz;

  int arow_l = wm + (lane & 15);
  int kb = (lane >> 4) * 8;

  for (int k0 = 0; k0 < FF; k0 += 32) {
    *(int4*)aw  = *(const int4*)(agp + k0);
    *(int4*)bw0 = *(const int4*)(bgp0 + k0);
    *(int4*)bw1 = *(const int4*)(bgp1 + k0);
    __syncthreads();
    bf16x8 a0 = *(bf16x8*)&As[arow_l * 32 + kb];
    bf16x8 a1 = *(bf16x8*)&As[(arow_l + 16) * 32 + kb];
#pragma unroll
    for (int n = 0; n < 4; n++) {
      int dc = wn + n * 16 + (lane & 15);
      bf16x8 bf = *(bf16x8*)&Bs[dc * 32 + kb];
      acc[0][n] = __builtin_amdgcn_mfma_f32_16x16x32_bf16(a0, bf, acc[0][n], 0, 0, 0);
      acc[1][n] = __builtin_amdgcn_mfma_f32_16x16x32_bf16(a1, bf, acc[1][n], 0, 0, 0);
    }
    __syncthreads();
  }

#pragma unroll
  for (int m = 0; m < 2; m++) {
    int rbase = row0 + wm + m * 16 + (lane >> 4) * 4;
#pragma unroll
    for (int reg = 0; reg < 4; reg++) {
      int r = rbase + reg;
      if (r > last) continue;
      int t = perm[r];
      size_t yrow = (size_t)t * DD;
#pragma unroll
      for (int n = 0; n < 4; n++) {
        int col = d0 + wn + n * 16 + (lane & 15);
        atomicAdd(&y[yrow + col], acc[m][n][reg]);
      }
    }
  }
}

extern "C" void kernel_launch(void* const* d_in, const int* in_sizes, int n_in,
                              void* d_out, int out_size, void* d_ws, size_t ws_size,
                              hipStream_t stream) {
  const float* x  = (const float*)d_in[0];
  const float* Wg = (const float*)d_in[1];
  const float* W  = (const float*)d_in[2];
  const float* V  = (const float*)d_in[3];
  const float* W2 = (const float*)d_in[4];
  float* y = (float*)d_out;

  char* ws = (char*)d_ws;
  size_t off = 0;
  auto alloc = [&](size_t n) -> char* {
    char* p = ws + off;
    off += (n + 255) & ~(size_t)255;
    return p;
  };
  unsigned short* xb  = (unsigned short*)alloc((size_t)TT * DD * 2);
  unsigned short* Wt  = (unsigned short*)alloc((size_t)EE * DD * FF * 2);
  unsigned short* Vt  = (unsigned short*)alloc((size_t)EE * DD * FF * 2);
  unsigned short* W2t = (unsigned short*)alloc((size_t)EE * DD * FF * 2);
  unsigned short* h   = (unsigned short*)alloc((size_t)TT * 2 * FF * 2);
  int*   perm = (int*)alloc(TT * 2 * 4);
  float* pw   = (float*)alloc(TT * 2 * 4);
  int*   te   = (int*)alloc(TT * 2 * 4);
  float* tw   = (float*)alloc(TT * 2 * 4);
  int*   ctrl = (int*)alloc(256);
  if (off > ws_size) return;  // insufficient scratch -> fail loudly (zero out)

  int n4 = TT * DD / 4;
  k_zero<<<2048, 256, 0, stream>>>((float4*)y, n4, ctrl);
  k_cvt_x<<<2048, 256, 0, stream>>>((const float4*)x, (ushort4*)xb, n4);
  // W,V: [E][D][F] -> [E][F][D]
  k_tcvt<<<dim3(FF / 32, DD / 32, EE), dim3(32, 8), 0, stream>>>(W, Wt, DD, FF);
  k_tcvt<<<dim3(FF / 32, DD / 32, EE), dim3(32, 8), 0, stream>>>(V, Vt, DD, FF);
  // W2: [E][F][D] -> [E][D][F]
  k_tcvt<<<dim3(DD / 32, FF / 32, EE), dim3(32, 8), 0, stream>>>(W2, W2t, FF, DD);
  k_gate<<<TT / 4, 256, 0, stream>>>(x, Wg, te, tw, ctrl);
  k_scan<<<1, 64, 0, stream>>>(ctrl);
  k_scatter<<<TT / 256, 256, 0, stream>>>(te, tw, ctrl, perm, pw);
  k_ffn1<<<dim3(128, FF / 128, EE), 256, 0, stream>>>(xb, Wt, Vt, perm, pw, ctrl, h);
  k_ffn2<<<dim3(128, DD / 128, EE), 256, 0, stream>>>(h, W2t, perm, ctrl, y);
}

// Round 2
// 351.456 us; speedup vs baseline: 1.6033x; 1.6033x over previous
//
#include <hip/hip_runtime.h>
#include <hip/hip_bf16.h>
#include <stdint.h>

// MoE: B=4,S=2048,D=512,F=2048,E=8,K=2.  T = B*S = 8192 tokens.
#define TT 8192
#define DD 512
#define FF 2048
#define EE 8

typedef __attribute__((ext_vector_type(8))) short bf16x8;
typedef __attribute__((ext_vector_type(4))) float f32x4;

static __device__ __forceinline__ unsigned short f2b(float f) {
  union { __hip_bfloat16 b; unsigned short u; } cv;
  cv.b = __float2bfloat16(f);
  return cv.u;
}

// async global->LDS, 16B per lane. LDS dest must be wave_base + lane*16.
static __device__ __forceinline__ void gload16(const void* g, void* l) {
  __builtin_amdgcn_global_load_lds(
      (const __attribute__((address_space(1))) unsigned int*)g,
      (__attribute__((address_space(3))) unsigned int*)l, 16, 0, 0);
}

// ---------------- zero y ----------------
__global__ void k_zero(float4* y4, int n4) {
  int i = blockIdx.x * blockDim.x + threadIdx.x;
  int stride = gridDim.x * blockDim.x;
  for (; i < n4; i += stride) y4[i] = make_float4(0.f, 0.f, 0.f, 0.f);
}

// ---------------- convert x -> bf16 ----------------
__global__ void k_cvt_x(const float4* x4, ushort4* xb4, int n4) {
  int i = blockIdx.x * blockDim.x + threadIdx.x;
  int stride = gridDim.x * blockDim.x;
  for (; i < n4; i += stride) {
    float4 v = x4[i];
    ushort4 o;
    o.x = f2b(v.x); o.y = f2b(v.y); o.z = f2b(v.z); o.w = f2b(v.w);
    xb4[i] = o;
  }
}

// ---------------- transpose+convert: in[e][M][N] f32 -> out[e][N][M] bf16 ----
__global__ void k_tcvt(const float* in, unsigned short* out, int M, int N) {
  __shared__ float tile[32][33];
  int z = blockIdx.z;
  const float* src = in + (size_t)z * M * N;
  unsigned short* dst = out + (size_t)z * M * N;
  int rb = blockIdx.y * 32, cb = blockIdx.x * 32;
  int tx = threadIdx.x, ty = threadIdx.y;
#pragma unroll
  for (int i = 0; i < 4; i++)
    tile[ty + i * 8][tx] = src[(size_t)(rb + ty + i * 8) * N + cb + tx];
  __syncthreads();
#pragma unroll
  for (int i = 0; i < 4; i++)
    dst[(size_t)(cb + ty + i * 8) * M + rb + tx] = f2b(tile[tx][ty + i * 8]);
}

// ---------------- gating: fp32 logits, top-2, softmax (NO atomics) ----------
__global__ void k_gate(const float* __restrict__ x, const float* __restrict__ Wg,
                       int* __restrict__ te, float* __restrict__ tw) {
  int wid = threadIdx.x >> 6, lane = threadIdx.x & 63;
  int t = blockIdx.x * 4 + wid;
  float acc[EE];
#pragma unroll
  for (int e = 0; e < EE; e++) acc[e] = 0.f;
  const float* xr = x + (size_t)t * DD;
#pragma unroll
  for (int it = 0; it < DD / 64; it++) {
    int d = it * 64 + lane;
    float xv = xr[d];
    const float* wg = Wg + d * EE;
    float4 a = *(const float4*)wg;
    float4 b = *(const float4*)(wg + 4);
    acc[0] += xv * a.x; acc[1] += xv * a.y; acc[2] += xv * a.z; acc[3] += xv * a.w;
    acc[4] += xv * b.x; acc[5] += xv * b.y; acc[6] += xv * b.z; acc[7] += xv * b.w;
  }
#pragma unroll
  for (int e = 0; e < EE; e++)
    for (int o = 32; o; o >>= 1) acc[e] += __shfl_xor(acc[e], o);
  if (lane == 0) {
    int e1 = 0; float v1 = acc[0];
#pragma unroll
    for (int e = 1; e < EE; e++) if (acc[e] > v1) { v1 = acc[e]; e1 = e; }
    int e2 = -1; float v2 = -INFINITY;
#pragma unroll
    for (int e = 0; e < EE; e++) if (e != e1 && acc[e] > v2) { v2 = acc[e]; e2 = e; }
    float ex = __expf(v2 - v1);
    float w1 = 1.f / (1.f + ex);
    float w2 = ex / (1.f + ex);
    te[t * 2] = e1; te[t * 2 + 1] = e2;
    tw[t * 2] = w1; tw[t * 2 + 1] = w2;
  }
}

// ---------------- routing: single-block deterministic counting sort --------
// 1024 threads, 16 slots each (slots = t*2+k, 16384 total).
__launch_bounds__(1024)
__global__ void k_route(const int* __restrict__ te, const float* __restrict__ tw,
                        int* __restrict__ ctrl, int* __restrict__ perm,
                        float* __restrict__ pw) {
  __shared__ int wsum[17][EE];
  __shared__ int ebase[EE];
  int tid = threadIdx.x;
  int lane = tid & 63, wid = tid >> 6;
  int myte[16]; float mytw[16];
  int c[EE];
#pragma unroll
  for (int e = 0; e < EE; e++) c[e] = 0;
  int s0 = tid * 16;
#pragma unroll
  for (int j = 0; j < 16; j++) {
    myte[j] = te[s0 + j];
    mytw[j] = tw[s0 + j];
#pragma unroll
    for (int e = 0; e < EE; e++) if (myte[j] == e) c[e]++;
  }
  // per-wave inclusive scan (per expert)
  int incl[EE];
#pragma unroll
  for (int e = 0; e < EE; e++) incl[e] = c[e];
  for (int off = 1; off < 64; off <<= 1) {
#pragma unroll
    for (int e = 0; e < EE; e++) {
      int v = __shfl_up(incl[e], off);
      if (lane >= off) incl[e] += v;
    }
  }
  if (lane == 63)
#pragma unroll
    for (int e = 0; e < EE; e++) wsum[wid][e] = incl[e];
  __syncthreads();
  if (tid < EE) {  // thread e: exclusive scan of 16 wave totals
    int s = 0;
    for (int w = 0; w < 16; w++) { int v = wsum[w][tid]; wsum[w][tid] = s; s += v; }
    wsum[16][tid] = s;
  }
  __syncthreads();
  if (tid == 0) {
    int s = 0;
#pragma unroll
    for (int e = 0; e < EE; e++) { ebase[e] = s; ctrl[8 + e] = s; s += wsum[16][e]; }
    ctrl[16] = s;
  }
  __syncthreads();
  // scatter: static per-expert loop to keep all indexing compile-time
#pragma unroll
  for (int e = 0; e < EE; e++) {
    int p = ebase[e] + wsum[wid][e] + incl[e] - c[e];
#pragma unroll
    for (int j = 0; j < 16; j++) {
      if (myte[j] == e) {
        perm[p] = (s0 + j) >> 1;
        pw[p] = mytw[j];
        p++;
      }
    }
  }
}

// ---------------- GEMM1: h[pos][f] = pw * silu(x@W) * (x@V)  (bf16 MFMA) ----
// Tile: 64 rows x 128 f-cols, BK=32. 4 waves (2x2). global_load_lds staging.
__launch_bounds__(256)
__global__ void k_ffn1(const unsigned short* __restrict__ xb,
                       const unsigned short* __restrict__ Wt,
                       const unsigned short* __restrict__ Vt,
                       const int* __restrict__ perm, const float* __restrict__ pw,
                       const int* __restrict__ ctrl, unsigned short* __restrict__ h) {
  int e = blockIdx.z, ftile = blockIdx.y, mt = blockIdx.x;
  int r0 = ctrl[8 + e], r1 = ctrl[9 + e];
  int row0 = r0 + mt * 64;
  if (row0 >= r1) return;
  int last = r1 - 1;

  __shared__ __align__(16) short As[64 * 32];
  __shared__ __align__(16) short Bw[128 * 32];
  __shared__ __align__(16) short Bv[128 * 32];

  int tid = threadIdx.x;
  int lane = tid & 63, wid = tid >> 6;
  int wm = (wid >> 1) * 32, wn = (wid & 1) * 64;

  int sArow = row0 + (tid >> 2);
  if (sArow > last) sArow = last;
  const unsigned short* agp = xb + (size_t)perm[sArow] * DD + (tid & 3) * 8;
  int f0 = ftile * 128;
  const unsigned short* wgp0 = Wt + ((size_t)e * FF + f0 + (tid >> 2)) * DD + (tid & 3) * 8;
  const unsigned short* wgp1 = wgp0 + (size_t)64 * DD;
  const unsigned short* vgp0 = Vt + ((size_t)e * FF + f0 + (tid >> 2)) * DD + (tid & 3) * 8;
  const unsigned short* vgp1 = vgp0 + (size_t)64 * DD;
  short* aw = &As[(tid >> 2) * 32 + (tid & 3) * 8];
  short* bw0 = &Bw[(tid >> 2) * 32 + (tid & 3) * 8];
  short* bw1 = bw0 + 64 * 32;
  short* bv0 = &Bv[(tid >> 2) * 32 + (tid & 3) * 8];
  short* bv1 = bv0 + 64 * 32;

  f32x4 zz = {0.f, 0.f, 0.f, 0.f};
  f32x4 accw[2][4], accv[2][4];
#pragma unroll
  for (int m = 0; m < 2; m++)
#pragma unroll
    for (int n = 0; n < 4; n++) { accw[m][n] = zz; accv[m][n] = zz; }

  int arow_l = wm + (lane & 15);
  int kb = (lane >> 4) * 8;

  for (int k0 = 0; k0 < DD; k0 += 32) {
    gload16(agp + k0, aw);
    gload16(wgp0 + k0, bw0);
    gload16(wgp1 + k0, bw1);
    gload16(vgp0 + k0, bv0);
    gload16(vgp1 + k0, bv1);
    __syncthreads();
    bf16x8 a0 = *(bf16x8*)&As[arow_l * 32 + kb];
    bf16x8 a1 = *(bf16x8*)&As[(arow_l + 16) * 32 + kb];
#pragma unroll
    for (int n = 0; n < 4; n++) {
      int fc = wn + n * 16 + (lane & 15);
      bf16x8 bwf = *(bf16x8*)&Bw[fc * 32 + kb];
      bf16x8 bvf = *(bf16x8*)&Bv[fc * 32 + kb];
      accw[0][n] = __builtin_amdgcn_mfma_f32_16x16x32_bf16(a0, bwf, accw[0][n], 0, 0, 0);
      accw[1][n] = __builtin_amdgcn_mfma_f32_16x16x32_bf16(a1, bwf, accw[1][n], 0, 0, 0);
      accv[0][n] = __builtin_amdgcn_mfma_f32_16x16x32_bf16(a0, bvf, accv[0][n], 0, 0, 0);
      accv[1][n] = __builtin_amdgcn_mfma_f32_16x16x32_bf16(a1, bvf, accv[1][n], 0, 0, 0);
    }
    __syncthreads();
  }

#pragma unroll
  for (int m = 0; m < 2; m++) {
    int rbase = row0 + wm + m * 16 + (lane >> 4) * 4;
#pragma unroll
    for (int reg = 0; reg < 4; reg++) {
      int r = rbase + reg;
      if (r > last) continue;
      float pwv = pw[r];
      size_t hrow = (size_t)r * FF;
#pragma unroll
      for (int n = 0; n < 4; n++) {
        float a = accw[m][n][reg];
        float b = accv[m][n][reg];
        float hv = a / (1.f + __expf(-a)) * b * pwv;
        int col = f0 + wn + n * 16 + (lane & 15);
        h[hrow + col] = f2b(hv);
      }
    }
  }
}

// ---------------- GEMM2: y[perm[pos]][d] += h[pos] @ W2t[e]  ----------------
__launch_bounds__(256)
__global__ void k_ffn2(const unsigned short* __restrict__ h,
                       const unsigned short* __restrict__ W2t,
                       const int* __restrict__ perm, const int* __restrict__ ctrl,
                       float* __restrict__ y) {
  int e = blockIdx.z, dt = blockIdx.y, mt = blockIdx.x;
  int r0 = ctrl[8 + e], r1 = ctrl[9 + e];
  int row0 = r0 + mt * 64;
  if (row0 >= r1) return;
  int last = r1 - 1;

  __shared__ __align__(16) short As[64 * 32];
  __shared__ __align__(16) short Bs[128 * 32];

  int tid = threadIdx.x;
  int lane = tid & 63, wid = tid >> 6;
  int wm = (wid >> 1) * 32, wn = (wid & 1) * 64;

  int sArow = row0 + (tid >> 2);
  if (sArow > last) sArow = last;
  const unsigned short* agp = h + (size_t)sArow * FF + (tid & 3) * 8;
  int d0 = dt * 128;
  const unsigned short* bgp0 = W2t + ((size_t)e * DD + d0 + (tid >> 2)) * FF + (tid & 3) * 8;
  const unsigned short* bgp1 = bgp0 + (size_t)64 * FF;
  short* aw = &As[(tid >> 2) * 32 + (tid & 3) * 8];
  short* bw0 = &Bs[(tid >> 2) * 32 + (tid & 3) * 8];
  short* bw1 = bw0 + 64 * 32;

  f32x4 zz = {0.f, 0.f, 0.f, 0.f};
  f32x4 acc[2][4];
#pragma unroll
  for (int m = 0; m < 2; m++)
#pragma unroll
    for (int n = 0; n < 4; n++) acc[m][n] = zz;

  int arow_l = wm + (lane & 15);
  int kb = (lane >> 4) * 8;

  for (int k0 = 0; k0 < FF; k0 += 32) {
    gload16(agp + k0, aw);
    gload16(bgp0 + k0, bw0);
    gload16(bgp1 + k0, bw1);
    __syncthreads();
    bf16x8 a0 = *(bf16x8*)&As[arow_l * 32 + kb];
    bf16x8 a1 = *(bf16x8*)&As[(arow_l + 16) * 32 + kb];
#pragma unroll
    for (int n = 0; n < 4; n++) {
      int dc = wn + n * 16 + (lane & 15);
      bf16x8 bf = *(bf16x8*)&Bs[dc * 32 + kb];
      acc[0][n] = __builtin_amdgcn_mfma_f32_16x16x32_bf16(a0, bf, acc[0][n], 0, 0, 0);
      acc[1][n] = __builtin_amdgcn_mfma_f32_16x16x32_bf16(a1, bf, acc[1][n], 0, 0, 0);
    }
    __syncthreads();
  }

#pragma unroll
  for (int m = 0; m < 2; m++) {
    int rbase = row0 + wm + m * 16 + (lane >> 4) * 4;
#pragma unroll
    for (int reg = 0; reg < 4; reg++) {
      int r = rbase + reg;
      if (r > last) continue;
      int t = perm[r];
      size_t yrow = (size_t)t * DD;
#pragma unroll
      for (int n = 0; n < 4; n++) {
        int col = d0 + wn + n * 16 + (lane & 15);
        atomicAdd(&y[yrow + col], acc[m][n][reg]);
      }
    }
  }
}

extern "C" void kernel_launch(void* const* d_in, const int* in_sizes, int n_in,
                              void* d_out, int out_size, void* d_ws, size_t ws_size,
                              hipStream_t stream) {
  const float* x  = (const float*)d_in[0];
  const float* Wg = (const float*)d_in[1];
  const float* W  = (const float*)d_in[2];
  const float* V  = (const float*)d_in[3];
  const float* W2 = (const float*)d_in[4];
  float* y = (float*)d_out;

  char* ws = (char*)d_ws;
  size_t off = 0;
  auto alloc = [&](size_t n) -> char* {
    char* p = ws + off;
    off += (n + 255) & ~(size_t)255;
    return p;
  };
  unsigned short* xb  = (unsigned short*)alloc((size_t)TT * DD * 2);
  unsigned short* Wt  = (unsigned short*)alloc((size_t)EE * DD * FF * 2);
  unsigned short* Vt  = (unsigned short*)alloc((size_t)EE * DD * FF * 2);
  unsigned short* W2t = (unsigned short*)alloc((size_t)EE * DD * FF * 2);
  unsigned short* h   = (unsigned short*)alloc((size_t)TT * 2 * FF * 2);
  int*   perm = (int*)alloc(TT * 2 * 4);
  float* pw   = (float*)alloc(TT * 2 * 4);
  int*   te   = (int*)alloc(TT * 2 * 4);
  float* tw   = (float*)alloc(TT * 2 * 4);
  int*   ctrl = (int*)alloc(256);
  if (off > ws_size) return;

  int n4 = TT * DD / 4;
  k_zero<<<2048, 256, 0, stream>>>((float4*)y, n4);
  k_cvt_x<<<2048, 256, 0, stream>>>((const float4*)x, (ushort4*)xb, n4);
  k_tcvt<<<dim3(FF / 32, DD / 32, EE), dim3(32, 8), 0, stream>>>(W, Wt, DD, FF);
  k_tcvt<<<dim3(FF / 32, DD / 32, EE), dim3(32, 8), 0, stream>>>(V, Vt, DD, FF);
  k_tcvt<<<dim3(DD / 32, FF / 32, EE), dim3(32, 8), 0, stream>>>(W2, W2t, FF, DD);
  k_gate<<<TT / 4, 256, 0, stream>>>(x, Wg, te, tw);
  k_route<<<1, 1024, 0, stream>>>(te, tw, ctrl, perm, pw);
  k_ffn1<<<dim3(128, FF / 128, EE), 256, 0, stream>>>(xb, Wt, Vt, perm, pw, ctrl, h);
  k_ffn2<<<dim3(128, DD / 128, EE), 256, 0, stream>>>(h, W2t, perm, ctrl, y);
}

// Round 3
// 316.470 us; speedup vs baseline: 1.7805x; 1.1106x over previous
//
#include <hip/hip_runtime.h>
#include <hip/hip_bf16.h>
#include <stdint.h>

// MoE: B=4,S=2048,D=512,F=2048,E=8,K=2.  T = B*S = 8192 tokens.
#define TT 8192
#define DD 512
#define FF 2048
#define EE 8
#define MAXT 136   // max row-tiles at BM=128: floor(16384/128)+8

typedef __attribute__((ext_vector_type(8))) short bf16x8;
typedef __attribute__((ext_vector_type(4))) float f32x4;

static __device__ __forceinline__ unsigned short f2b(float f) {
  union { __hip_bfloat16 b; unsigned short u; } cv;
  cv.b = __float2bfloat16(f);
  return cv.u;
}

// async global->LDS, 16B per lane. LDS dest must be wave_base + lane*16.
static __device__ __forceinline__ void gload16(const void* g, void* l) {
  __builtin_amdgcn_global_load_lds(
      (const __attribute__((address_space(1))) unsigned int*)g,
      (__attribute__((address_space(3))) unsigned int*)l, 16, 0, 0);
}

// ---------------- zero y ----------------
__global__ void k_zero(float4* y4, int n4) {
  int i = blockIdx.x * blockDim.x + threadIdx.x;
  int stride = gridDim.x * blockDim.x;
  for (; i < n4; i += stride) y4[i] = make_float4(0.f, 0.f, 0.f, 0.f);
}

// ---------------- convert x -> bf16 ----------------
__global__ void k_cvt_x(const float4* x4, ushort4* xb4, int n4) {
  int i = blockIdx.x * blockDim.x + threadIdx.x;
  int stride = gridDim.x * blockDim.x;
  for (; i < n4; i += stride) {
    float4 v = x4[i];
    ushort4 o;
    o.x = f2b(v.x); o.y = f2b(v.y); o.z = f2b(v.z); o.w = f2b(v.w);
    xb4[i] = o;
  }
}

// ---------------- transpose+convert: in[e][M][N] f32 -> out[e][N][M] bf16 ----
__global__ void k_tcvt(const float* in, unsigned short* out, int M, int N) {
  __shared__ float tile[32][33];
  int z = blockIdx.z;
  const float* src = in + (size_t)z * M * N;
  unsigned short* dst = out + (size_t)z * M * N;
  int rb = blockIdx.y * 32, cb = blockIdx.x * 32;
  int tx = threadIdx.x, ty = threadIdx.y;
#pragma unroll
  for (int i = 0; i < 4; i++)
    tile[ty + i * 8][tx] = src[(size_t)(rb + ty + i * 8) * N + cb + tx];
  __syncthreads();
#pragma unroll
  for (int i = 0; i < 4; i++)
    dst[(size_t)(cb + ty + i * 8) * M + rb + tx] = f2b(tile[tx][ty + i * 8]);
}

// ---------------- gating: fp32 logits, top-2, softmax (NO atomics) ----------
__global__ void k_gate(const float* __restrict__ x, const float* __restrict__ Wg,
                       int* __restrict__ te, float* __restrict__ tw) {
  int wid = threadIdx.x >> 6, lane = threadIdx.x & 63;
  int t = blockIdx.x * 4 + wid;
  float acc[EE];
#pragma unroll
  for (int e = 0; e < EE; e++) acc[e] = 0.f;
  const float* xr = x + (size_t)t * DD;
#pragma unroll
  for (int it = 0; it < DD / 64; it++) {
    int d = it * 64 + lane;
    float xv = xr[d];
    const float* wg = Wg + d * EE;
    float4 a = *(const float4*)wg;
    float4 b = *(const float4*)(wg + 4);
    acc[0] += xv * a.x; acc[1] += xv * a.y; acc[2] += xv * a.z; acc[3] += xv * a.w;
    acc[4] += xv * b.x; acc[5] += xv * b.y; acc[6] += xv * b.z; acc[7] += xv * b.w;
  }
#pragma unroll
  for (int e = 0; e < EE; e++)
    for (int o = 32; o; o >>= 1) acc[e] += __shfl_xor(acc[e], o);
  if (lane == 0) {
    int e1 = 0; float v1 = acc[0];
#pragma unroll
    for (int e = 1; e < EE; e++) if (acc[e] > v1) { v1 = acc[e]; e1 = e; }
    int e2 = -1; float v2 = -INFINITY;
#pragma unroll
    for (int e = 0; e < EE; e++) if (e != e1 && acc[e] > v2) { v2 = acc[e]; e2 = e; }
    float ex = __expf(v2 - v1);
    float w1 = 1.f / (1.f + ex);
    float w2 = ex / (1.f + ex);
    te[t * 2] = e1; te[t * 2 + 1] = e2;
    tw[t * 2] = w1; tw[t * 2 + 1] = w2;
  }
}

// ---------------- routing: single-block deterministic counting sort --------
__launch_bounds__(1024)
__global__ void k_route(const int* __restrict__ te, const float* __restrict__ tw,
                        int* __restrict__ ctrl, int* __restrict__ perm,
                        float* __restrict__ pw, int* __restrict__ tileE,
                        int* __restrict__ tileRow) {
  __shared__ int wsum[17][EE];
  __shared__ int ebase[EE];
  int tid = threadIdx.x;
  int lane = tid & 63, wid = tid >> 6;
  int myte[16]; float mytw[16];
  int c[EE];
#pragma unroll
  for (int e = 0; e < EE; e++) c[e] = 0;
  int s0 = tid * 16;
#pragma unroll
  for (int j = 0; j < 16; j++) {
    myte[j] = te[s0 + j];
    mytw[j] = tw[s0 + j];
#pragma unroll
    for (int e = 0; e < EE; e++) if (myte[j] == e) c[e]++;
  }
  int incl[EE];
#pragma unroll
  for (int e = 0; e < EE; e++) incl[e] = c[e];
  for (int off = 1; off < 64; off <<= 1) {
#pragma unroll
    for (int e = 0; e < EE; e++) {
      int v = __shfl_up(incl[e], off);
      if (lane >= off) incl[e] += v;
    }
  }
  if (lane == 63)
#pragma unroll
    for (int e = 0; e < EE; e++) wsum[wid][e] = incl[e];
  __syncthreads();
  if (tid < EE) {
    int s = 0;
    for (int w = 0; w < 16; w++) { int v = wsum[w][tid]; wsum[w][tid] = s; s += v; }
    wsum[16][tid] = s;
  }
  __syncthreads();
  if (tid == 0) {
    int s = 0, nt = 0;
    for (int e = 0; e < EE; e++) {
      int cnt = wsum[16][e];
      ebase[e] = s; ctrl[8 + e] = s; ctrl[e] = cnt;
      for (int i = 0; i < cnt; i += 128) { tileE[nt] = e; tileRow[nt] = s + i; nt++; }
      s += cnt;
    }
    ctrl[16] = s; ctrl[17] = nt;
  }
  __syncthreads();
#pragma unroll
  for (int e = 0; e < EE; e++) {
    int p = ebase[e] + wsum[wid][e] + incl[e] - c[e];
#pragma unroll
    for (int j = 0; j < 16; j++) {
      if (myte[j] == e) {
        perm[p] = (s0 + j) >> 1;
        pw[p] = mytw[j];
        p++;
      }
    }
  }
}

// ---------------- GEMM1: h[pos][f] = pw * silu(x@W) * (x@V) -----------------
// BM=128 rows x 64 f-cols (W and V both -> 128 LDS B-rows), BK=32.
// 4 waves split M; each wave: 32 rows x 64 f x {W,V} -> acc[2][8].
__launch_bounds__(256)
__global__ void k_ffn1(const unsigned short* __restrict__ xb,
                       const unsigned short* __restrict__ Wt,
                       const unsigned short* __restrict__ Vt,
                       const int* __restrict__ perm, const float* __restrict__ pw,
                       const int* __restrict__ ctrl, const int* __restrict__ tileE,
                       const int* __restrict__ tileRow,
                       unsigned short* __restrict__ h) {
  int ti = blockIdx.y;
  if (ti >= ctrl[17]) return;
  int e = tileE[ti];
  int row0 = tileRow[ti];
  int last = ctrl[8 + e] + ctrl[e] - 1;
  int f0 = blockIdx.x * 64;

  __shared__ __align__(16) short As[128 * 32];
  __shared__ __align__(16) short Bs[128 * 32];  // rows 0..63 = W, 64..127 = V

  int tid = threadIdx.x;
  int lane = tid & 63, wid = tid >> 6;

  // A staging: 512 slots of 16B; thread covers slot tid and tid+256
  int s2 = tid + 256;
  int arow1 = row0 + (tid >> 2); if (arow1 > last) arow1 = last;
  int arow2 = row0 + (s2 >> 2);  if (arow2 > last) arow2 = last;
  const unsigned short* agp1 = xb + (size_t)perm[arow1] * DD + (tid & 3) * 8;
  const unsigned short* agp2 = xb + (size_t)perm[arow2] * DD + (s2 & 3) * 8;
  // B staging: W rows 0..63 (256 slots), V rows 0..63 (256 slots)
  const unsigned short* wgp = Wt + ((size_t)e * FF + f0 + (tid >> 2)) * DD + (tid & 3) * 8;
  const unsigned short* vgp = Vt + ((size_t)e * FF + f0 + (tid >> 2)) * DD + (tid & 3) * 8;
  short* aw1 = &As[tid * 8];
  short* aw2 = &As[s2 * 8];
  short* bwp = &Bs[tid * 8];
  short* bvp = &Bs[64 * 32 + tid * 8];

  f32x4 zz = {0.f, 0.f, 0.f, 0.f};
  f32x4 accw[2][4], accv[2][4];
#pragma unroll
  for (int m = 0; m < 2; m++)
#pragma unroll
    for (int n = 0; n < 4; n++) { accw[m][n] = zz; accv[m][n] = zz; }

  int lrow = lane & 15, kb = (lane >> 4) * 8;
  int abase = (wid * 32 + lrow) * 32 + kb;

  for (int k0 = 0; k0 < DD; k0 += 32) {
    gload16(agp1 + k0, aw1);
    gload16(agp2 + k0, aw2);
    gload16(wgp + k0, bwp);
    gload16(vgp + k0, bvp);
    __syncthreads();
    bf16x8 a0 = *(bf16x8*)&As[abase];
    bf16x8 a1 = *(bf16x8*)&As[abase + 16 * 32];
#pragma unroll
    for (int n = 0; n < 4; n++) {
      bf16x8 bw = *(bf16x8*)&Bs[(n * 16 + lrow) * 32 + kb];
      bf16x8 bv = *(bf16x8*)&Bs[(64 + n * 16 + lrow) * 32 + kb];
      accw[0][n] = __builtin_amdgcn_mfma_f32_16x16x32_bf16(a0, bw, accw[0][n], 0, 0, 0);
      accw[1][n] = __builtin_amdgcn_mfma_f32_16x16x32_bf16(a1, bw, accw[1][n], 0, 0, 0);
      accv[0][n] = __builtin_amdgcn_mfma_f32_16x16x32_bf16(a0, bv, accv[0][n], 0, 0, 0);
      accv[1][n] = __builtin_amdgcn_mfma_f32_16x16x32_bf16(a1, bv, accv[1][n], 0, 0, 0);
    }
    __syncthreads();
  }

#pragma unroll
  for (int m = 0; m < 2; m++) {
    int rbase = row0 + wid * 32 + m * 16 + (lane >> 4) * 4;
#pragma unroll
    for (int reg = 0; reg < 4; reg++) {
      int r = rbase + reg;
      if (r > last) continue;
      float pwv = pw[r];
      size_t hrow = (size_t)r * FF;
#pragma unroll
      for (int n = 0; n < 4; n++) {
        float a = accw[m][n][reg];
        float b = accv[m][n][reg];
        float hv = a / (1.f + __expf(-a)) * b * pwv;
        h[hrow + f0 + n * 16 + lrow] = f2b(hv);
      }
    }
  }
}

// ---------------- GEMM2: y[perm[pos]][d] += h[pos] @ W2t[e] -----------------
// m97 structure: 128x128 tile, BK=32 over K=F=2048, 4 waves 2x2, acc[4][4].
__launch_bounds__(256)
__global__ void k_ffn2(const unsigned short* __restrict__ h,
                       const unsigned short* __restrict__ W2t,
                       const int* __restrict__ perm, const int* __restrict__ ctrl,
                       const int* __restrict__ tileE, const int* __restrict__ tileRow,
                       float* __restrict__ y) {
  int ti = blockIdx.y;
  if (ti >= ctrl[17]) return;
  int e = tileE[ti];
  int row0 = tileRow[ti];
  int last = ctrl[8 + e] + ctrl[e] - 1;
  int d0 = blockIdx.x * 128;

  __shared__ __align__(16) short As[128 * 32];
  __shared__ __align__(16) short Bs[128 * 32];

  int tid = threadIdx.x;
  int lane = tid & 63, wid = tid >> 6;
  int wm = (wid >> 1) * 64, wn = (wid & 1) * 64;

  int s2 = tid + 256;
  int arow1 = row0 + (tid >> 2); if (arow1 > last) arow1 = last;
  int arow2 = row0 + (s2 >> 2);  if (arow2 > last) arow2 = last;
  const unsigned short* agp1 = h + (size_t)arow1 * FF + (tid & 3) * 8;
  const unsigned short* agp2 = h + (size_t)arow2 * FF + (s2 & 3) * 8;
  const unsigned short* bgp1 = W2t + ((size_t)e * DD + d0 + (tid >> 2)) * FF + (tid & 3) * 8;
  const unsigned short* bgp2 = W2t + ((size_t)e * DD + d0 + 64 + (tid >> 2)) * FF + (tid & 3) * 8;
  short* aw1 = &As[tid * 8];
  short* aw2 = &As[s2 * 8];
  short* bw1 = &Bs[tid * 8];
  short* bw2 = &Bs[64 * 32 + tid * 8];

  f32x4 zz = {0.f, 0.f, 0.f, 0.f};
  f32x4 acc[4][4];
#pragma unroll
  for (int m = 0; m < 4; m++)
#pragma unroll
    for (int n = 0; n < 4; n++) acc[m][n] = zz;

  int lrow = lane & 15, kb = (lane >> 4) * 8;

  for (int k0 = 0; k0 < FF; k0 += 32) {
    gload16(agp1 + k0, aw1);
    gload16(agp2 + k0, aw2);
    gload16(bgp1 + k0, bw1);
    gload16(bgp2 + k0, bw2);
    __syncthreads();
    bf16x8 a[4], b[4];
#pragma unroll
    for (int m = 0; m < 4; m++) a[m] = *(bf16x8*)&As[(wm + m * 16 + lrow) * 32 + kb];
#pragma unroll
    for (int n = 0; n < 4; n++) b[n] = *(bf16x8*)&Bs[(wn + n * 16 + lrow) * 32 + kb];
#pragma unroll
    for (int m = 0; m < 4; m++)
#pragma unroll
      for (int n = 0; n < 4; n++)
        acc[m][n] = __builtin_amdgcn_mfma_f32_16x16x32_bf16(a[m], b[n], acc[m][n], 0, 0, 0);
    __syncthreads();
  }

#pragma unroll
  for (int m = 0; m < 4; m++) {
    int rbase = row0 + wm + m * 16 + (lane >> 4) * 4;
#pragma unroll
    for (int reg = 0; reg < 4; reg++) {
      int r = rbase + reg;
      if (r > last) continue;
      int t = perm[r];
      size_t yrow = (size_t)t * DD;
#pragma unroll
      for (int n = 0; n < 4; n++)
        atomicAdd(&y[yrow + d0 + wn + n * 16 + lrow], acc[m][n][reg]);
    }
  }
}

extern "C" void kernel_launch(void* const* d_in, const int* in_sizes, int n_in,
                              void* d_out, int out_size, void* d_ws, size_t ws_size,
                              hipStream_t stream) {
  const float* x  = (const float*)d_in[0];
  const float* Wg = (const float*)d_in[1];
  const float* W  = (const float*)d_in[2];
  const float* V  = (const float*)d_in[3];
  const float* W2 = (const float*)d_in[4];
  float* y = (float*)d_out;

  char* ws = (char*)d_ws;
  size_t off = 0;
  auto alloc = [&](size_t n) -> char* {
    char* p = ws + off;
    off += (n + 255) & ~(size_t)255;
    return p;
  };
  unsigned short* xb  = (unsigned short*)alloc((size_t)TT * DD * 2);
  unsigned short* Wt  = (unsigned short*)alloc((size_t)EE * DD * FF * 2);
  unsigned short* Vt  = (unsigned short*)alloc((size_t)EE * DD * FF * 2);
  unsigned short* W2t = (unsigned short*)alloc((size_t)EE * DD * FF * 2);
  unsigned short* h   = (unsigned short*)alloc((size_t)TT * 2 * FF * 2);
  int*   perm = (int*)alloc(TT * 2 * 4);
  float* pw   = (float*)alloc(TT * 2 * 4);
  int*   te   = (int*)alloc(TT * 2 * 4);
  float* tw   = (float*)alloc(TT * 2 * 4);
  int*   ctrl = (int*)alloc(256);
  int*   tileE   = (int*)alloc(MAXT * 4);
  int*   tileRow = (int*)alloc(MAXT * 4);
  if (off > ws_size) return;

  int n4 = TT * DD / 4;
  k_zero<<<2048, 256, 0, stream>>>((float4*)y, n4);
  k_cvt_x<<<2048, 256, 0, stream>>>((const float4*)x, (ushort4*)xb, n4);
  k_tcvt<<<dim3(FF / 32, DD / 32, EE), dim3(32, 8), 0, stream>>>(W, Wt, DD, FF);
  k_tcvt<<<dim3(FF / 32, DD / 32, EE), dim3(32, 8), 0, stream>>>(V, Vt, DD, FF);
  k_tcvt<<<dim3(DD / 32, FF / 32, EE), dim3(32, 8), 0, stream>>>(W2, W2t, FF, DD);
  k_gate<<<TT / 4, 256, 0, stream>>>(x, Wg, te, tw);
  k_route<<<1, 1024, 0, stream>>>(te, tw, ctrl, perm, pw, tileE, tileRow);
  k_ffn1<<<dim3(FF / 64, MAXT), 256, 0, stream>>>(xb, Wt, Vt, perm, pw, ctrl, tileE, tileRow, h);
  k_ffn2<<<dim3(DD / 128, MAXT), 256, 0, stream>>>(h, W2t, perm, ctrl, tileE, tileRow, y);
}

// Round 4
// 255.905 us; speedup vs baseline: 2.2019x; 1.2367x over previous
//
#include <hip/hip_runtime.h>
#include <hip/hip_bf16.h>
#include <stdint.h>

// MoE: B=4,S=2048,D=512,F=2048,E=8,K=2.  T = B*S = 8192 tokens.
#define TT 8192
#define DD 512
#define FF 2048
#define EE 8
#define MAXT 136   // max row-tiles at BM=128

typedef __attribute__((ext_vector_type(8))) short bf16x8;
typedef __attribute__((ext_vector_type(4))) float f32x4;

static __device__ __forceinline__ unsigned short f2b(float f) {
  union { __hip_bfloat16 b; unsigned short u; } cv;
  cv.b = __float2bfloat16(f);
  return cv.u;
}

// async global->LDS, 16B per lane. LDS dest must be wave_base + lane*16.
static __device__ __forceinline__ void gload16(const void* g, void* l) {
  __builtin_amdgcn_global_load_lds(
      (const __attribute__((address_space(1))) unsigned int*)g,
      (__attribute__((address_space(3))) unsigned int*)l, 16, 0, 0);
}

// ---------------- prep: gate logits (fp32) + x->bf16 + zero y ---------------
__launch_bounds__(256)
__global__ void k_prep(const float* __restrict__ x, const float* __restrict__ Wg,
                       unsigned short* __restrict__ xb, float* __restrict__ y,
                       int* __restrict__ te, float* __restrict__ tw) {
  int wid = threadIdx.x >> 6, lane = threadIdx.x & 63;
  int t = blockIdx.x * 4 + wid;
  const float* xr = x + (size_t)t * DD;
  unsigned short* xbr = xb + (size_t)t * DD;
  float* yr = y + (size_t)t * DD;
  int d0 = lane * 8;

  float4 v0 = *(const float4*)(xr + d0);
  float4 v1 = *(const float4*)(xr + d0 + 4);
  ushort4 o0, o1;
  o0.x = f2b(v0.x); o0.y = f2b(v0.y); o0.z = f2b(v0.z); o0.w = f2b(v0.w);
  o1.x = f2b(v1.x); o1.y = f2b(v1.y); o1.z = f2b(v1.z); o1.w = f2b(v1.w);
  *(ushort4*)(xbr + d0) = o0;
  *(ushort4*)(xbr + d0 + 4) = o1;
  float4 z4 = make_float4(0.f, 0.f, 0.f, 0.f);
  *(float4*)(yr + d0) = z4;
  *(float4*)(yr + d0 + 4) = z4;

  float xv[8] = {v0.x, v0.y, v0.z, v0.w, v1.x, v1.y, v1.z, v1.w};
  float acc[EE];
#pragma unroll
  for (int e = 0; e < EE; e++) acc[e] = 0.f;
#pragma unroll
  for (int j = 0; j < 8; j++) {
    const float* wg = Wg + (size_t)(d0 + j) * EE;
    float4 a = *(const float4*)wg;
    float4 b = *(const float4*)(wg + 4);
    acc[0] += xv[j] * a.x; acc[1] += xv[j] * a.y; acc[2] += xv[j] * a.z; acc[3] += xv[j] * a.w;
    acc[4] += xv[j] * b.x; acc[5] += xv[j] * b.y; acc[6] += xv[j] * b.z; acc[7] += xv[j] * b.w;
  }
#pragma unroll
  for (int e = 0; e < EE; e++)
    for (int o = 32; o; o >>= 1) acc[e] += __shfl_xor(acc[e], o);
  if (lane == 0) {
    int e1 = 0; float v1m = acc[0];
#pragma unroll
    for (int e = 1; e < EE; e++) if (acc[e] > v1m) { v1m = acc[e]; e1 = e; }
    int e2 = -1; float v2m = -INFINITY;
#pragma unroll
    for (int e = 0; e < EE; e++) if (e != e1 && acc[e] > v2m) { v2m = acc[e]; e2 = e; }
    float ex = __expf(v2m - v1m);
    float w1 = 1.f / (1.f + ex);
    float w2 = ex / (1.f + ex);
    te[t * 2] = e1; te[t * 2 + 1] = e2;
    tw[t * 2] = w1; tw[t * 2 + 1] = w2;
  }
}

// ------------- transpose+convert all weights, one launch (z=0..23) ----------
__global__ void k_tcvt_all(const float* __restrict__ W, const float* __restrict__ V,
                           const float* __restrict__ W2, unsigned short* __restrict__ Wt,
                           unsigned short* __restrict__ Vt, unsigned short* __restrict__ W2t) {
  __shared__ float tile[32][33];
  int z = blockIdx.y;
  const float* src; unsigned short* dst; int N, nbx;
  if (z < 16) {
    int e = z & 7;
    size_t base = (size_t)e * DD * FF;
    src = (z < 8 ? W : V) + base;
    dst = (z < 8 ? Wt : Vt) + base;
    N = FF; nbx = FF / 32;          // in [DD][FF] -> out [FF][DD]
  } else {
    int e = z - 16;
    size_t base = (size_t)e * DD * FF;
    src = W2 + base; dst = W2t + base;
    N = DD; nbx = DD / 32;          // in [FF][DD] -> out [DD][FF]
  }
  int M = (z < 16) ? DD : FF;
  int bx = blockIdx.x;
  int cb = (bx % nbx) * 32, rb = (bx / nbx) * 32;
  int tx = threadIdx.x, ty = threadIdx.y;
#pragma unroll
  for (int i = 0; i < 4; i++)
    tile[ty + i * 8][tx] = src[(size_t)(rb + ty + i * 8) * N + cb + tx];
  __syncthreads();
#pragma unroll
  for (int i = 0; i < 4; i++)
    dst[(size_t)(cb + ty + i * 8) * M + rb + tx] = f2b(tile[tx][ty + i * 8]);
}

// ---------------- routing: single-block deterministic counting sort --------
__launch_bounds__(1024)
__global__ void k_route(const int* __restrict__ te, const float* __restrict__ tw,
                        int* __restrict__ ctrl, int* __restrict__ perm,
                        float* __restrict__ pw, int* __restrict__ tileE,
                        int* __restrict__ tileRow) {
  __shared__ int wsum[17][EE];
  __shared__ int ebase[EE];
  int tid = threadIdx.x;
  int lane = tid & 63, wid = tid >> 6;
  int myte[16]; float mytw[16];
  int c[EE];
#pragma unroll
  for (int e = 0; e < EE; e++) c[e] = 0;
  int s0 = tid * 16;
#pragma unroll
  for (int j = 0; j < 16; j++) {
    myte[j] = te[s0 + j];
    mytw[j] = tw[s0 + j];
#pragma unroll
    for (int e = 0; e < EE; e++) if (myte[j] == e) c[e]++;
  }
  int incl[EE];
#pragma unroll
  for (int e = 0; e < EE; e++) incl[e] = c[e];
  for (int off = 1; off < 64; off <<= 1) {
#pragma unroll
    for (int e = 0; e < EE; e++) {
      int v = __shfl_up(incl[e], off);
      if (lane >= off) incl[e] += v;
    }
  }
  if (lane == 63)
#pragma unroll
    for (int e = 0; e < EE; e++) wsum[wid][e] = incl[e];
  __syncthreads();
  if (tid < EE) {
    int s = 0;
    for (int w = 0; w < 16; w++) { int v = wsum[w][tid]; wsum[w][tid] = s; s += v; }
    wsum[16][tid] = s;
  }
  __syncthreads();
  if (tid == 0) {
    int s = 0, nt = 0;
    for (int e = 0; e < EE; e++) {
      int cnt = wsum[16][e];
      ebase[e] = s; ctrl[8 + e] = s; ctrl[e] = cnt;
      for (int i = 0; i < cnt; i += 128) { tileE[nt] = e; tileRow[nt] = s + i; nt++; }
      s += cnt;
    }
    ctrl[16] = s; ctrl[17] = nt;
  }
  __syncthreads();
#pragma unroll
  for (int e = 0; e < EE; e++) {
    int p = ebase[e] + wsum[wid][e] + incl[e] - c[e];
#pragma unroll
    for (int j = 0; j < 16; j++) {
      if (myte[j] == e) {
        perm[p] = (s0 + j) >> 1;
        pw[p] = mytw[j];
        p++;
      }
    }
  }
}

// ---------------- GEMM1: h[pos][f] = pw * silu(x@W) * (x@V) -----------------
// BM=128 x (64 W-cols | 64 V-cols), BK=32, 4 waves split M.
// 2-phase pipeline: double-buffered LDS, stage(next) before compute(cur).
__launch_bounds__(256)
__global__ void k_ffn1(const unsigned short* __restrict__ xb,
                       const unsigned short* __restrict__ Wt,
                       const unsigned short* __restrict__ Vt,
                       const int* __restrict__ perm, const float* __restrict__ pw,
                       const int* __restrict__ ctrl, const int* __restrict__ tileE,
                       const int* __restrict__ tileRow,
                       unsigned short* __restrict__ h) {
  int ti = blockIdx.y;
  if (ti >= ctrl[17]) return;
  int e = tileE[ti];
  int row0 = tileRow[ti];
  int last = ctrl[8 + e] + ctrl[e] - 1;
  int f0 = blockIdx.x * 64;

  __shared__ __align__(16) short As[2][128 * 32];
  __shared__ __align__(16) short Bs[2][128 * 32];

  int tid = threadIdx.x;
  int lane = tid & 63, wid = tid >> 6;

  int ar1 = row0 + (tid >> 2); if (ar1 > last) ar1 = last;
  int ar2 = row0 + (tid >> 2) + 64; if (ar2 > last) ar2 = last;
  const unsigned short* agp1 = xb + (size_t)perm[ar1] * DD + (tid & 3) * 8;
  const unsigned short* agp2 = xb + (size_t)perm[ar2] * DD + (tid & 3) * 8;
  const unsigned short* wgp = Wt + ((size_t)e * FF + f0 + (tid >> 2)) * DD + (tid & 3) * 8;
  const unsigned short* vgp = Vt + ((size_t)e * FF + f0 + (tid >> 2)) * DD + (tid & 3) * 8;

#define STAGE1(buf, k0) do { \
    gload16(agp1 + (k0), &As[buf][tid * 8]); \
    gload16(agp2 + (k0), &As[buf][(tid + 256) * 8]); \
    gload16(wgp + (k0), &Bs[buf][tid * 8]); \
    gload16(vgp + (k0), &Bs[buf][(tid + 256) * 8]); \
  } while (0)

  f32x4 zz = {0.f, 0.f, 0.f, 0.f};
  f32x4 accw[2][4], accv[2][4];
#pragma unroll
  for (int m = 0; m < 2; m++)
#pragma unroll
    for (int n = 0; n < 4; n++) { accw[m][n] = zz; accv[m][n] = zz; }

  int lrow = lane & 15, kb = (lane >> 4) * 8;
  int a0off = (wid * 32 + lrow) * 32 + kb;

#define COMP1(buf) do { \
    bf16x8 a0 = *(bf16x8*)&As[buf][a0off]; \
    bf16x8 a1 = *(bf16x8*)&As[buf][a0off + 16 * 32]; \
    _Pragma("unroll") \
    for (int n = 0; n < 4; n++) { \
      bf16x8 bw = *(bf16x8*)&Bs[buf][(n * 16 + lrow) * 32 + kb]; \
      bf16x8 bv = *(bf16x8*)&Bs[buf][(64 + n * 16 + lrow) * 32 + kb]; \
      accw[0][n] = __builtin_amdgcn_mfma_f32_16x16x32_bf16(a0, bw, accw[0][n], 0, 0, 0); \
      accw[1][n] = __builtin_amdgcn_mfma_f32_16x16x32_bf16(a1, bw, accw[1][n], 0, 0, 0); \
      accv[0][n] = __builtin_amdgcn_mfma_f32_16x16x32_bf16(a0, bv, accv[0][n], 0, 0, 0); \
      accv[1][n] = __builtin_amdgcn_mfma_f32_16x16x32_bf16(a1, bv, accv[1][n], 0, 0, 0); \
    } \
  } while (0)

  STAGE1(0, 0);
  __syncthreads();
#pragma unroll 1
  for (int ks = 0; ks < 16; ks += 2) {
    if (ks + 1 < 16) STAGE1(1, (ks + 1) * 32);
    COMP1(0);
    __syncthreads();
    if (ks + 2 < 16) STAGE1(0, (ks + 2) * 32);
    COMP1(1);
    __syncthreads();
  }
#undef STAGE1
#undef COMP1

#pragma unroll
  for (int m = 0; m < 2; m++) {
    int rbase = row0 + wid * 32 + m * 16 + (lane >> 4) * 4;
#pragma unroll
    for (int reg = 0; reg < 4; reg++) {
      int r = rbase + reg;
      if (r > last) continue;
      float pwv = pw[r];
      size_t hrow = (size_t)r * FF;
#pragma unroll
      for (int n = 0; n < 4; n++) {
        float a = accw[m][n][reg];
        float b = accv[m][n][reg];
        float hv = a / (1.f + __expf(-a)) * b * pwv;
        h[hrow + f0 + n * 16 + lrow] = f2b(hv);
      }
    }
  }
}

// ---------------- GEMM2: y[perm[pos]][d] += h[pos] @ W2t[e] -----------------
// 128x128 tile, BK=32 over K=F=2048, 4 waves 2x2, acc[4][4], 2-phase dbuf.
__launch_bounds__(256)
__global__ void k_ffn2(const unsigned short* __restrict__ h,
                       const unsigned short* __restrict__ W2t,
                       const int* __restrict__ perm, const int* __restrict__ ctrl,
                       const int* __restrict__ tileE, const int* __restrict__ tileRow,
                       float* __restrict__ y) {
  int ti = blockIdx.y;
  if (ti >= ctrl[17]) return;
  int e = tileE[ti];
  int row0 = tileRow[ti];
  int last = ctrl[8 + e] + ctrl[e] - 1;
  int d0 = blockIdx.x * 128;

  __shared__ __align__(16) short As[2][128 * 32];
  __shared__ __align__(16) short Bs[2][128 * 32];

  int tid = threadIdx.x;
  int lane = tid & 63, wid = tid >> 6;
  int wm = (wid >> 1) * 64, wn = (wid & 1) * 64;

  int ar1 = row0 + (tid >> 2); if (ar1 > last) ar1 = last;
  int ar2 = row0 + (tid >> 2) + 64; if (ar2 > last) ar2 = last;
  const unsigned short* agp1 = h + (size_t)ar1 * FF + (tid & 3) * 8;
  const unsigned short* agp2 = h + (size_t)ar2 * FF + (tid & 3) * 8;
  const unsigned short* bgp1 = W2t + ((size_t)e * DD + d0 + (tid >> 2)) * FF + (tid & 3) * 8;
  const unsigned short* bgp2 = bgp1 + (size_t)64 * FF;

#define STAGE2(buf, k0) do { \
    gload16(agp1 + (k0), &As[buf][tid * 8]); \
    gload16(agp2 + (k0), &As[buf][(tid + 256) * 8]); \
    gload16(bgp1 + (k0), &Bs[buf][tid * 8]); \
    gload16(bgp2 + (k0), &Bs[buf][(tid + 256) * 8]); \
  } while (0)

  f32x4 zz = {0.f, 0.f, 0.f, 0.f};
  f32x4 acc[4][4];
#pragma unroll
  for (int m = 0; m < 4; m++)
#pragma unroll
    for (int n = 0; n < 4; n++) acc[m][n] = zz;

  int lrow = lane & 15, kb = (lane >> 4) * 8;

#define COMP2(buf) do { \
    bf16x8 a[4], b[4]; \
    _Pragma("unroll") \
    for (int m = 0; m < 4; m++) a[m] = *(bf16x8*)&As[buf][(wm + m * 16 + lrow) * 32 + kb]; \
    _Pragma("unroll") \
    for (int n = 0; n < 4; n++) b[n] = *(bf16x8*)&Bs[buf][(wn + n * 16 + lrow) * 32 + kb]; \
    _Pragma("unroll") \
    for (int m = 0; m < 4; m++) \
      _Pragma("unroll") \
      for (int n = 0; n < 4; n++) \
        acc[m][n] = __builtin_amdgcn_mfma_f32_16x16x32_bf16(a[m], b[n], acc[m][n], 0, 0, 0); \
  } while (0)

  STAGE2(0, 0);
  __syncthreads();
#pragma unroll 1
  for (int ks = 0; ks < 64; ks += 2) {
    if (ks + 1 < 64) STAGE2(1, (ks + 1) * 32);
    COMP2(0);
    __syncthreads();
    if (ks + 2 < 64) STAGE2(0, (ks + 2) * 32);
    COMP2(1);
    __syncthreads();
  }
#undef STAGE2
#undef COMP2

#pragma unroll
  for (int m = 0; m < 4; m++) {
    int rbase = row0 + wm + m * 16 + (lane >> 4) * 4;
#pragma unroll
    for (int reg = 0; reg < 4; reg++) {
      int r = rbase + reg;
      if (r > last) continue;
      int t = perm[r];
      size_t yrow = (size_t)t * DD;
#pragma unroll
      for (int n = 0; n < 4; n++)
        atomicAdd(&y[yrow + d0 + wn + n * 16 + lrow], acc[m][n][reg]);
    }
  }
}

extern "C" void kernel_launch(void* const* d_in, const int* in_sizes, int n_in,
                              void* d_out, int out_size, void* d_ws, size_t ws_size,
                              hipStream_t stream) {
  const float* x  = (const float*)d_in[0];
  const float* Wg = (const float*)d_in[1];
  const float* W  = (const float*)d_in[2];
  const float* V  = (const float*)d_in[3];
  const float* W2 = (const float*)d_in[4];
  float* y = (float*)d_out;

  char* ws = (char*)d_ws;
  size_t off = 0;
  auto alloc = [&](size_t n) -> char* {
    char* p = ws + off;
    off += (n + 255) & ~(size_t)255;
    return p;
  };
  unsigned short* xb  = (unsigned short*)alloc((size_t)TT * DD * 2);
  unsigned short* Wt  = (unsigned short*)alloc((size_t)EE * DD * FF * 2);
  unsigned short* Vt  = (unsigned short*)alloc((size_t)EE * DD * FF * 2);
  unsigned short* W2t = (unsigned short*)alloc((size_t)EE * DD * FF * 2);
  unsigned short* h   = (unsigned short*)alloc((size_t)TT * 2 * FF * 2);
  int*   perm = (int*)alloc(TT * 2 * 4);
  float* pw   = (float*)alloc(TT * 2 * 4);
  int*   te   = (int*)alloc(TT * 2 * 4);
  float* tw   = (float*)alloc(TT * 2 * 4);
  int*   ctrl = (int*)alloc(256);
  int*   tileE   = (int*)alloc(MAXT * 4);
  int*   tileRow = (int*)alloc(MAXT * 4);
  if (off > ws_size) return;

  k_prep<<<TT / 4, 256, 0, stream>>>(x, Wg, xb, y, te, tw);
  k_tcvt_all<<<dim3(1024, 24), dim3(32, 8), 0, stream>>>(W, V, W2, Wt, Vt, W2t);
  k_route<<<1, 1024, 0, stream>>>(te, tw, ctrl, perm, pw, tileE, tileRow);
  k_ffn1<<<dim3(FF / 64, MAXT), 256, 0, stream>>>(xb, Wt, Vt, perm, pw, ctrl, tileE, tileRow, h);
  k_ffn2<<<dim3(DD / 128, MAXT), 256, 0, stream>>>(h, W2t, perm, ctrl, tileE, tileRow, y);
}